// Round 9
// baseline (486.032 us; speedup 1.0000x reference)
//
#include <hip/hip_runtime.h>

typedef unsigned short u16;
typedef __attribute__((ext_vector_type(8))) short bf8_t;   // 8 bf16 in 4 VGPRs
typedef __attribute__((ext_vector_type(4))) float f4_t;

constexpr int NN   = 50000;
constexpr int NE   = 800000;
constexpr int TBLN = 2048;
constexpr int MB64 = (NN + 63) / 64;  // 782 ip blocks (64-row tiles)
constexpr int FB   = NE / 256;        // 3125 fill blocks
constexpr int TBB  = TBLN / 2;        // 1024 table blocks (2 t-values each)

// ---------- helpers ----------
__device__ __forceinline__ u16 f2b(float f) {
  unsigned u = __float_as_uint(f);
  unsigned r = u + 0x7fffu + ((u >> 16) & 1u);  // RNE
  return (u16)(r >> 16);
}
__device__ __forceinline__ u16 f2h(float f) {
  _Float16 h = (_Float16)f;
  return __builtin_bit_cast(unsigned short, h);
}
__device__ __forceinline__ float h2f(u16 v) {
  _Float16 h = __builtin_bit_cast(_Float16, v);
  return (float)h;
}
__device__ __forceinline__ unsigned packh(float a, float b) {
  return (unsigned)f2h(a) | ((unsigned)f2h(b) << 16);
}
__device__ __forceinline__ float blo(unsigned u) { return __uint_as_float(u << 16); }
__device__ __forceinline__ float bhi(unsigned u) { return __uint_as_float(u & 0xffff0000u); }
__device__ __forceinline__ float wred64(float v) {
#pragma unroll
  for (int o = 32; o; o >>= 1) v += __shfl_xor(v, o);
  return v;
}
__device__ __forceinline__ int iwred64(int v) {
#pragma unroll
  for (int o = 32; o; o >>= 1) v += __shfl_xor(v, o);
  return v;
}
__device__ __forceinline__ bf8_t ldv(const u16* p) { return *(const bf8_t*)p; }
__device__ __forceinline__ f4_t mfma16(bf8_t a, bf8_t b, f4_t c) {
  return __builtin_amdgcn_mfma_f32_16x16x32_bf16(a, b, c, 0, 0, 0);
}

// ---------- prep: transposes + deg histogram + x->bf16 + a_edge table ----------
// (build_table folded in as a block range; each table block recomputes its own
//  V slice in identical fp32 order -> bit-identical tbl, no V dependency)
__global__ __launch_bounds__(256) void prep_k(
    const float* __restrict__ ew1, const float* __restrict__ ate1,
    const float* __restrict__ ew2, const float* __restrict__ ate2,
    const float* __restrict__ w1, const float* __restrict__ w2,
    const float* __restrict__ gw1, const float* __restrict__ gw2,
    u16* __restrict__ w1t, u16* __restrict__ w2t,
    u16* __restrict__ g1wt, u16* __restrict__ g2wt,
    const int* __restrict__ dstv, int* __restrict__ deg,
    const float* __restrict__ x, u16* __restrict__ x16,
    const float* __restrict__ taw1, const float* __restrict__ tab1,
    const float* __restrict__ talnw, const float* __restrict__ talnb,
    const float* __restrict__ taw2, const float* __restrict__ tab2,
    float* __restrict__ tbl) {
  __shared__ float tpart[2][4];
  __shared__ float tush[2][128];
  __shared__ float tpacc[2][16];
  const int bid = blockIdx.x, t = threadIdx.x;
  if (bid < 384) {
    int idx = bid * 256 + t;
    if (idx < 32768) {
      int r = idx >> 8, c = idx & 255;
      w1t[c * 128 + r] = f2b(w1[idx]);
    } else if (idx < 65536) {
      int k = idx - 32768;
      int r = k >> 7, c = k & 127;
      w2t[c * 256 + r] = f2b(w2[k]);
    } else if (idx < 81920) {
      int k = idx - 65536;
      int r = k >> 7, c = k & 127;
      g1wt[c * 128 + r] = f2b(gw1[k]);
    } else {
      int k = idx - 81920;
      int r = k >> 7, c = k & 127;
      g2wt[c * 128 + r] = f2b(gw2[k]);
    }
  } else if (bid < 384 + FB) {
    int e = (bid - 384) * 256 + t;
    if (e < NE) atomicAdd(&deg[dstv[e]], 1);
  } else if (bid < 384 + 2 * FB) {
    // x (fp32) -> x16 (bf16), 8 elems/thread, exact grid (3125 blocks)
    int idx = (bid - 384 - FB) * 256 + t;
    size_t e8 = (size_t)idx * 8;
    const float4 a = *(const float4*)(x + e8);
    const float4 b = *(const float4*)(x + e8 + 4);
    uint4 o;
    o.x = (unsigned)f2b(a.x) | ((unsigned)f2b(a.y) << 16);
    o.y = (unsigned)f2b(a.z) | ((unsigned)f2b(a.w) << 16);
    o.z = (unsigned)f2b(b.x) | ((unsigned)f2b(b.y) << 16);
    o.w = (unsigned)f2b(b.z) | ((unsigned)f2b(b.w) << 16);
    *(uint4*)(x16 + e8) = o;
  } else {
    // a_edge(t) table: 2 t-values per block (half = 128 threads, 2 waves each)
    const int tb = bid - (384 + 2 * FB);
    const int half = t >> 7, j = t & 127;
    const int ln = t & 63, wvh = (t >> 6) & 1;
    const float tv = (float)(tb * 2 + half) / (float)(TBLN - 1);
    // local V slice: thread j needs V[j][0..7] (identical fp32 order as before)
    float Vloc[8];
#pragma unroll
    for (int p = 0; p < 4; ++p) {
      float s1 = 0.f, s2 = 0.f;
      for (int c = 0; c < 32; ++c) {
        s1 += ew1[j * 128 + p * 32 + c] * ate1[p * 32 + c];
        s2 += ew2[j * 128 + p * 32 + c] * ate2[p * 32 + c];
      }
      Vloc[p] = s1;
      Vloc[4 + p] = s2;
    }
    float v = tv * taw1[j] + tab1[j];
    float s = wred64(v), sq = wred64(v * v);
    if (ln == 0) { tpart[half][wvh * 2] = s; tpart[half][wvh * 2 + 1] = sq; }
    __syncthreads();
    float S = tpart[half][0] + tpart[half][2], SQ = tpart[half][1] + tpart[half][3];
    float mu = S * (1.f / 128.f);
    float var = SQ * (1.f / 128.f) - mu * mu;
    float rstd = rsqrtf(var + 1e-5f);
    float u = fmaxf((v - mu) * rstd * talnw[j] + talnb[j], 0.f);
    tush[half][j] = u;
    __syncthreads();
    float acc = 0.f;
    for (int k = 0; k < 128; ++k) acc += tush[half][k] * taw2[k * 128 + j];
    float w = tanhf(acc + tab2[j]);
    w = fminf(fmaxf(w, -3.f), 3.f);
#pragma unroll
    for (int p = 0; p < 8; ++p) {
      float z = wred64(w * Vloc[p]);
      if (ln == 0) tpacc[half][wvh * 8 + p] = z;
    }
    __syncthreads();
    if (j < 8) tbl[(tb * 2 + half) * 8 + j] = tpacc[half][j] + tpacc[half][8 + j];
  }
}

// ---------- scans ----------
__global__ __launch_bounds__(512) void scan1(const int* __restrict__ deg,
                                             int* __restrict__ indptr,
                                             int* __restrict__ blks) {
  const int t = threadIdx.x;
  const int i = blockIdx.x * 512 + t;
  int v = (i < NN) ? deg[i] : 0;
  const int lane = t & 63, wv = t >> 6;
  int x = v;
#pragma unroll
  for (int o = 1; o < 64; o <<= 1) {
    int y = __shfl_up(x, o);
    if (lane >= o) x += y;
  }
  __shared__ int ws[8];
  if (lane == 63) ws[wv] = x;
  __syncthreads();
  if (t < 8) {
    int y = ws[t];
#pragma unroll
    for (int o = 1; o < 8; o <<= 1) {
      int z = __shfl_up(y, o);
      if (t >= o) y += z;
    }
    ws[t] = y;
  }
  __syncthreads();
  int excl = wv ? ws[wv - 1] : 0;
  x += excl;
  if (i < NN) indptr[i + 1] = x;
  if (t == 511) blks[blockIdx.x] = x;
}
// scan23: fuses scan2 (block-offset scan, done redundantly per block as a sum
// of preceding block totals) + scan3 (apply offsets, seed cursor).
__global__ __launch_bounds__(512) void scan23(int* __restrict__ indptr,
                                              const int* __restrict__ blks,
                                              const int* __restrict__ deg,
                                              int* __restrict__ cursor, int nb) {
  const int t = threadIdx.x;
  int v = (t < nb && t < blockIdx.x) ? blks[t] : 0;
  const int wv = t >> 6;
  int x = iwred64(v);
  __shared__ int ws[8];
  if ((t & 63) == 0) ws[wv] = x;
  __syncthreads();
  int prefix = ws[0] + ws[1] + ws[2] + ws[3] + ws[4] + ws[5] + ws[6] + ws[7];
  const int i = blockIdx.x * 512 + t;
  if (i < NN) {
    int val = indptr[i + 1] + prefix;
    indptr[i + 1] = val;
    cursor[i] = val - deg[i];
  }
  if (i == 0) indptr[0] = 0;
}

// ---------- CSR fill body (lerp + 20B record); zero LDS use ----------
__device__ void fill_body(int fb, const int* __restrict__ srcv,
                          const int* __restrict__ dstv,
                          const float* __restrict__ etime,
                          const float* __restrict__ tbl,
                          int* __restrict__ cursor,
                          u16* __restrict__ recs) {
  const int e = fb * 256 + threadIdx.x;
  if (e >= NE) return;
  int d = dstv[e];
  int pos = atomicAdd(&cursor[d], 1);
  float t = etime[e];
  t = fminf(fmaxf(t, 0.f), 1.f);
  float fpos = t * (float)(TBLN - 1);
  int i0 = (int)fpos;
  if (i0 > TBLN - 2) i0 = TBLN - 2;
  float fr = fpos - (float)i0;
  const float4* r = (const float4*)(tbl + i0 * 8);
  float4 a0 = r[0], a1 = r[1], b0 = r[2], b1 = r[3];
  float4 o1, o2;
  o1.x = a0.x + fr * (b0.x - a0.x); o1.y = a0.y + fr * (b0.y - a0.y);
  o1.z = a0.z + fr * (b0.z - a0.z); o1.w = a0.w + fr * (b0.w - a0.w);
  o2.x = a1.x + fr * (b1.x - a1.x); o2.y = a1.y + fr * (b1.y - a1.y);
  o2.z = a1.z + fr * (b1.z - a1.z); o2.w = a1.w + fr * (b1.w - a1.w);
  u16* rp = recs + (size_t)pos * 16;
  uint4 w;
  w.x = (unsigned)srcv[e];
  w.y = packh(o1.x, o1.y);
  w.z = packh(o1.z, o1.w);
  w.w = packh(o2.x, o2.y);
  *(uint4*)rp = w;
  *(unsigned*)(rp + 8) = packh(o2.z, o2.w);
}

// 64-row register-LN input projection + fused hp1 (GEMM3 from LDS).
// LDS: h1n[64][264] bf16 (h2n[64][136] aliased) + partS/partQ [4][64] f32
__device__ void ip_body(int ipb, char* smem,
                        const u16* __restrict__ x16, const u16* __restrict__ w1t,
                        const float* __restrict__ b1, const float* __restrict__ ln1w,
                        const float* __restrict__ ln1b, const u16* __restrict__ w2t,
                        const float* __restrict__ b2, const float* __restrict__ pnw,
                        const float* __restrict__ pnb, u16* __restrict__ h16,
                        const u16* __restrict__ g1wt, const float* __restrict__ attsrc,
                        const float* __restrict__ attdst, u16* __restrict__ hp16,
                        float* __restrict__ asrc, float* __restrict__ adst) {
  u16* h1n = (u16*)smem;                        // [64][264] bf16
  u16* h2n = h1n;                               // alias, [64][136] after GEMM2
  float* partS = (float*)(smem + 33792);        // [4][64]
  float* partQ = (float*)(smem + 33792 + 1024); // [4][64]

  const int t = threadIdx.x;
  const int w = t >> 6, lane = t & 63, q = lane >> 4, l15 = lane & 15;
  const int rowbase = ipb * 64;

  // ---- GEMM1: [64,128] @ [128,256] ----
  f4_t acc[4][4];
#pragma unroll
  for (int mt = 0; mt < 4; ++mt)
#pragma unroll
    for (int nt = 0; nt < 4; ++nt) acc[mt][nt] = (f4_t){0.f, 0.f, 0.f, 0.f};
#pragma unroll
  for (int kst = 0; kst < 4; ++kst) {
    int k0 = kst * 32 + q * 8;
    bf8_t a[4];
#pragma unroll
    for (int mt = 0; mt < 4; ++mt) {
      int r = rowbase + mt * 16 + l15;
      if (r > NN - 1) r = NN - 1;
      a[mt] = ldv(x16 + (size_t)r * 128 + k0);
    }
#pragma unroll
    for (int nt = 0; nt < 4; ++nt) {
      int n = w * 64 + nt * 16 + l15;
      bf8_t b = ldv(w1t + n * 128 + k0);
#pragma unroll
      for (int mt = 0; mt < 4; ++mt)
        acc[mt][nt] = mfma16(a[mt], b, acc[mt][nt]);
    }
  }
  // bias + relu in regs
#pragma unroll
  for (int nt = 0; nt < 4; ++nt) {
    float bb = b1[w * 64 + nt * 16 + l15];
#pragma unroll
    for (int mt = 0; mt < 4; ++mt)
#pragma unroll
      for (int r = 0; r < 4; ++r)
        acc[mt][nt][r] = fmaxf(acc[mt][nt][r] + bb, 0.f);
  }
  // per-(mt,r) partial row sums over this wave's 64 cols
  {
    float s[4][4], sq[4][4];
#pragma unroll
    for (int mt = 0; mt < 4; ++mt)
#pragma unroll
      for (int r = 0; r < 4; ++r) {
        float a0 = acc[mt][0][r], b0 = acc[mt][1][r], c0 = acc[mt][2][r], d0 = acc[mt][3][r];
        s[mt][r] = a0 + b0 + c0 + d0;
        sq[mt][r] = a0 * a0 + b0 * b0 + c0 * c0 + d0 * d0;
      }
#pragma unroll
    for (int o = 1; o < 16; o <<= 1)
#pragma unroll
      for (int mt = 0; mt < 4; ++mt)
#pragma unroll
        for (int r = 0; r < 4; ++r) {
          s[mt][r] += __shfl_xor(s[mt][r], o);
          sq[mt][r] += __shfl_xor(sq[mt][r], o);
        }
    if (l15 == 0) {
#pragma unroll
      for (int mt = 0; mt < 4; ++mt)
#pragma unroll
        for (int r = 0; r < 4; ++r) {
          int row = mt * 16 + q * 4 + r;
          partS[w * 64 + row] = s[mt][r];
          partQ[w * 64 + row] = sq[mt][r];
        }
    }
  }
  __syncthreads();
  // LN1 from registers -> h1n (bf16)
  {
    float lw[4], lb[4];
#pragma unroll
    for (int nt = 0; nt < 4; ++nt) {
      int col = w * 64 + nt * 16 + l15;
      lw[nt] = ln1w[col]; lb[nt] = ln1b[col];
    }
#pragma unroll
    for (int mt = 0; mt < 4; ++mt)
#pragma unroll
      for (int r = 0; r < 4; ++r) {
        int row = mt * 16 + q * 4 + r;
        float S = partS[row] + partS[64 + row] + partS[128 + row] + partS[192 + row];
        float Q = partQ[row] + partQ[64 + row] + partQ[128 + row] + partQ[192 + row];
        float mu = S * (1.f / 256.f);
        float var = Q * (1.f / 256.f) - mu * mu;
        float rstd = rsqrtf(var + 1e-5f);
#pragma unroll
        for (int nt = 0; nt < 4; ++nt) {
          int col = w * 64 + nt * 16 + l15;
          h1n[row * 264 + col] = f2b((acc[mt][nt][r] - mu) * rstd * lw[nt] + lb[nt]);
        }
      }
  }
  __syncthreads();
  // ---- GEMM2: [64,256] @ [256,128] ----
  f4_t acc2[4][2];
#pragma unroll
  for (int mt = 0; mt < 4; ++mt)
#pragma unroll
    for (int nt = 0; nt < 2; ++nt) acc2[mt][nt] = (f4_t){0.f, 0.f, 0.f, 0.f};
#pragma unroll
  for (int kst = 0; kst < 8; ++kst) {
    int k0 = kst * 32 + q * 8;
    bf8_t a[4];
#pragma unroll
    for (int mt = 0; mt < 4; ++mt)
      a[mt] = ldv(h1n + (mt * 16 + l15) * 264 + k0);
#pragma unroll
    for (int nt = 0; nt < 2; ++nt) {
      int n = w * 32 + nt * 16 + l15;
      bf8_t b = ldv(w2t + n * 256 + k0);
#pragma unroll
      for (int mt = 0; mt < 4; ++mt)
        acc2[mt][nt] = mfma16(a[mt], b, acc2[mt][nt]);
    }
  }
  // bias in regs, partial sums
#pragma unroll
  for (int nt = 0; nt < 2; ++nt) {
    float bb = b2[w * 32 + nt * 16 + l15];
#pragma unroll
    for (int mt = 0; mt < 4; ++mt)
#pragma unroll
      for (int r = 0; r < 4; ++r)
        acc2[mt][nt][r] += bb;
  }
  {
    float s[4][4], sq[4][4];
#pragma unroll
    for (int mt = 0; mt < 4; ++mt)
#pragma unroll
      for (int r = 0; r < 4; ++r) {
        float a0 = acc2[mt][0][r], b0 = acc2[mt][1][r];
        s[mt][r] = a0 + b0;
        sq[mt][r] = a0 * a0 + b0 * b0;
      }
#pragma unroll
    for (int o = 1; o < 16; o <<= 1)
#pragma unroll
      for (int mt = 0; mt < 4; ++mt)
#pragma unroll
        for (int r = 0; r < 4; ++r) {
          s[mt][r] += __shfl_xor(s[mt][r], o);
          sq[mt][r] += __shfl_xor(sq[mt][r], o);
        }
    __syncthreads();  // all GEMM2 h1n reads done
    if (l15 == 0) {
#pragma unroll
      for (int mt = 0; mt < 4; ++mt)
#pragma unroll
        for (int r = 0; r < 4; ++r) {
          int row = mt * 16 + q * 4 + r;
          partS[w * 64 + row] = s[mt][r];
          partQ[w * 64 + row] = sq[mt][r];
        }
    }
  }
  __syncthreads();
  // LN2 + relu + clip -> h2n[64][136] (aliased on h1n; safe after sync)
  {
    float lw[2], lb[2];
#pragma unroll
    for (int nt = 0; nt < 2; ++nt) {
      int col = w * 32 + nt * 16 + l15;
      lw[nt] = pnw[col]; lb[nt] = pnb[col];
    }
#pragma unroll
    for (int mt = 0; mt < 4; ++mt)
#pragma unroll
      for (int r = 0; r < 4; ++r) {
        int row = mt * 16 + q * 4 + r;
        float S = partS[row] + partS[64 + row] + partS[128 + row] + partS[192 + row];
        float Q = partQ[row] + partQ[64 + row] + partQ[128 + row] + partQ[192 + row];
        float mu = S * (1.f / 128.f);
        float var = Q * (1.f / 128.f) - mu * mu;
        float rstd = rsqrtf(var + 1e-5f);
#pragma unroll
        for (int nt = 0; nt < 2; ++nt) {
          int col = w * 32 + nt * 16 + l15;
          float v = (acc2[mt][nt][r] - mu) * rstd * lw[nt] + lb[nt];
          v = fminf(fmaxf(v, 0.f), 10.f);
          h2n[row * 136 + col] = f2b(v);
        }
      }
  }
  __syncthreads();
  // coalesced h16 stores: 64 rows x 128 cols bf16
  {
    const int row = t >> 2, cb = (t & 3) * 32;
    int rg = rowbase + row;
    if (rg < NN) {
#pragma unroll
      for (int c = 0; c < 4; ++c) {
        uint4 v0 = *(const uint4*)(h2n + row * 136 + cb + c * 8);
        *(uint4*)(h16 + (size_t)rg * 128 + cb + c * 8) = v0;
      }
    }
  }
  // ---- GEMM3 (fused hp1): [64,128] @ [128,128] -> hp16, asrc, adst ----
  f4_t acc3[4][2];
#pragma unroll
  for (int mt = 0; mt < 4; ++mt)
#pragma unroll
    for (int nt = 0; nt < 2; ++nt) acc3[mt][nt] = (f4_t){0.f, 0.f, 0.f, 0.f};
#pragma unroll
  for (int kst = 0; kst < 4; ++kst) {
    int k0 = kst * 32 + q * 8;
    bf8_t a[4];
#pragma unroll
    for (int mt = 0; mt < 4; ++mt)
      a[mt] = ldv(h2n + (mt * 16 + l15) * 136 + k0);
#pragma unroll
    for (int nt = 0; nt < 2; ++nt) {
      int n = w * 32 + nt * 16 + l15;
      bf8_t b = ldv(g1wt + n * 128 + k0);
#pragma unroll
      for (int mt = 0; mt < 4; ++mt)
        acc3[mt][nt] = mfma16(a[mt], b, acc3[mt][nt]);
    }
  }
  {
    float ps[4][4], pd[4][4];
#pragma unroll
    for (int mt = 0; mt < 4; ++mt)
#pragma unroll
      for (int r = 0; r < 4; ++r) { ps[mt][r] = 0.f; pd[mt][r] = 0.f; }
#pragma unroll
    for (int mt = 0; mt < 4; ++mt)
#pragma unroll
      for (int nt = 0; nt < 2; ++nt) {
        int col = w * 32 + nt * 16 + l15;
        float as = attsrc[col], ad = attdst[col];
#pragma unroll
        for (int r = 0; r < 4; ++r) {
          int row = mt * 16 + q * 4 + r;
          int rg = rowbase + row;
          float v = acc3[mt][nt][r];
          if (rg < NN) hp16[(size_t)rg * 128 + col] = f2b(v);
          ps[mt][r] += v * as;
          pd[mt][r] += v * ad;
        }
      }
#pragma unroll
    for (int o = 1; o < 16; o <<= 1)
#pragma unroll
      for (int mt = 0; mt < 4; ++mt)
#pragma unroll
        for (int r = 0; r < 4; ++r) {
          ps[mt][r] += __shfl_xor(ps[mt][r], o);
          pd[mt][r] += __shfl_xor(pd[mt][r], o);
        }
    if (l15 == 0) {
#pragma unroll
      for (int mt = 0; mt < 4; ++mt)
#pragma unroll
        for (int r = 0; r < 4; ++r) {
          int rg = rowbase + mt * 16 + q * 4 + r;
          if (rg < NN) {
            asrc[rg * 4 + w] = ps[mt][r];
            adst[rg * 4 + w] = pd[mt][r];
          }
        }
    }
  }
}

__global__ __launch_bounds__(256) void fillip_k(
    const int* srcv, const int* dstv, const float* etime, const float* tbl,
    int* cursor, u16* recs,
    const u16* x16, const u16* w1t, const float* b1, const float* ln1w,
    const float* ln1b, const u16* w2t, const float* b2, const float* pnw,
    const float* pnb, u16* h16,
    const u16* g1wt, const float* g1as, const float* g1ad,
    u16* hp16, float* asrc, float* adst) {
  __shared__ char smem[35840];
  const int bid = blockIdx.x;
  if (bid % 5 == 0) {
    ip_body(bid / 5, smem, x16, w1t, b1, ln1w, ln1b, w2t, b2, pnw, pnb, h16,
            g1wt, g1as, g1ad, hp16, asrc, adst);
  } else {
    fill_body(bid - bid / 5 - 1, srcv, dstv, etime, tbl, cursor, recs);
  }
}

// ---------- standalone hp (layer 2): node projection + attention logits ----------
__global__ __launch_bounds__(256) void hp_mfma(
    const u16* __restrict__ feat16, const u16* __restrict__ wt,
    const float* __restrict__ attsrc, const float* __restrict__ attdst,
    u16* __restrict__ hp16, float* __restrict__ asrc, float* __restrict__ adst) {
  const int t = threadIdx.x;
  const int w = t >> 6, lane = t & 63, q = lane >> 4, l15 = lane & 15;
  const int rowbase = blockIdx.x * 64;
  f4_t acc[4][2];
#pragma unroll
  for (int mt = 0; mt < 4; ++mt)
#pragma unroll
    for (int nt = 0; nt < 2; ++nt) acc[mt][nt] = (f4_t){0.f, 0.f, 0.f, 0.f};
#pragma unroll
  for (int kst = 0; kst < 4; ++kst) {
    int k0 = kst * 32 + q * 8;
    bf8_t a[4];
#pragma unroll
    for (int mt = 0; mt < 4; ++mt) {
      int r = rowbase + mt * 16 + l15;
      if (r > NN - 1) r = NN - 1;
      a[mt] = ldv(feat16 + (size_t)r * 128 + k0);
    }
#pragma unroll
    for (int nt = 0; nt < 2; ++nt) {
      int n = w * 32 + nt * 16 + l15;
      bf8_t b = ldv(wt + n * 128 + k0);
#pragma unroll
      for (int mt = 0; mt < 4; ++mt)
        acc[mt][nt] = mfma16(a[mt], b, acc[mt][nt]);
    }
  }
  float ps[4][4], pd[4][4];
#pragma unroll
  for (int mt = 0; mt < 4; ++mt)
#pragma unroll
    for (int r = 0; r < 4; ++r) { ps[mt][r] = 0.f; pd[mt][r] = 0.f; }
#pragma unroll
  for (int mt = 0; mt < 4; ++mt)
#pragma unroll
    for (int nt = 0; nt < 2; ++nt) {
      int col = w * 32 + nt * 16 + l15;
      float as = attsrc[col], ad = attdst[col];
#pragma unroll
      for (int r = 0; r < 4; ++r) {
        int row = mt * 16 + q * 4 + r;
        int rg = rowbase + row;
        float v = acc[mt][nt][r];
        if (rg < NN) hp16[(size_t)rg * 128 + col] = f2b(v);
        ps[mt][r] += v * as;
        pd[mt][r] += v * ad;
      }
    }
#pragma unroll
  for (int o = 1; o < 16; o <<= 1)
#pragma unroll
    for (int mt = 0; mt < 4; ++mt)
#pragma unroll
      for (int r = 0; r < 4; ++r) {
        ps[mt][r] += __shfl_xor(ps[mt][r], o);
        pd[mt][r] += __shfl_xor(pd[mt][r], o);
      }
  if (l15 == 0) {
#pragma unroll
    for (int mt = 0; mt < 4; ++mt)
#pragma unroll
      for (int r = 0; r < 4; ++r) {
        int rg = rowbase + mt * 16 + q * 4 + r;
        if (rg < NN) {
          asrc[rg * 4 + w] = ps[mt][r];
          adst[rg * 4 + w] = pd[mt][r];
        }
      }
  }
}

// ---------- GAT aggregation: 1-deep record prefetch pipeline ----------
template <int L, int FINAL>
__global__ __launch_bounds__(256) void agg_k(
    const int* __restrict__ indptr, const u16* __restrict__ recs,
    const float* __restrict__ asrc, const float* __restrict__ adst,
    const u16* __restrict__ hp16, const u16* __restrict__ feat16,
    const float* __restrict__ gbias, const float* __restrict__ lnw,
    const float* __restrict__ lnb, u16* __restrict__ gout16,
    float* __restrict__ out32) {
  const int wv = threadIdx.x >> 6, lane = threadIdx.x & 63;
  const int n = blockIdx.x * 4 + wv;
  if (n >= NN) return;
  const int s0 = indptr[n], s1 = indptr[n + 1];
  const int dg = s1 - s0;
  const int g = lane >> 4, sl = lane & 15, cb = sl * 8, hdB = sl >> 2;
  const float advB = adst[n * 4 + hdB];
  float ssp = 0.f, sap = 0.f;
  float acc[8];
#pragma unroll
  for (int i = 0; i < 8; ++i) acc[i] = 0.f;
  const int s1m1 = s1 - 1;
  // preload first iteration's records
  int pi0 = s0 + g, pi1 = s0 + 4 + g;
  int pj0 = pi0 < s1 ? pi0 : s1m1, pj1 = pi1 < s1 ? pi1 : s1m1;
  uint4 ra0 = *(const uint4*)(recs + (size_t)pj0 * 16);
  unsigned rb0 = *(const unsigned*)(recs + (size_t)pj0 * 16 + 8);
  uint4 ra1 = *(const uint4*)(recs + (size_t)pj1 * 16);
  unsigned rb1 = *(const unsigned*)(recs + (size_t)pj1 * 16 + 8);
  for (int base = s0; base < s1; base += 8) {
    // issue next iteration's record loads before the dependent row gathers
    uint4 nra0 = ra0, nra1 = ra1;
    unsigned nrb0 = rb0, nrb1 = rb1;
    int nbase = base + 8;
    if (nbase < s1) {
      int ni0 = nbase + g, ni1 = nbase + 4 + g;
      int nj0 = ni0 < s1 ? ni0 : s1m1, nj1 = ni1 < s1 ? ni1 : s1m1;
      nra0 = *(const uint4*)(recs + (size_t)nj0 * 16);
      nrb0 = *(const unsigned*)(recs + (size_t)nj0 * 16 + 8);
      nra1 = *(const uint4*)(recs + (size_t)nj1 * 16);
      nrb1 = *(const unsigned*)(recs + (size_t)nj1 * 16 + 8);
    }
    int i0 = base + g, i1 = base + 4 + g;
    int sc0 = (int)ra0.x, sc1 = (int)ra1.x;
    // attr extraction: u16 index 2+4L+hdB
    //  L0: words {ra.y (u16 2,3), ra.z (u16 4,5)};  L1: {ra.w (u16 6,7), rb (u16 8,9)}
    unsigned w00, w01, w10, w11;
    if (L == 0) { w00 = ra0.y; w01 = ra0.z; w10 = ra1.y; w11 = ra1.z; }
    else        { w00 = ra0.w; w01 = rb0;   w10 = ra1.w; w11 = rb1; }
    unsigned sel0 = (hdB & 2) ? w01 : w00;
    unsigned sel1 = (hdB & 2) ? w11 : w10;
    float ae0 = h2f((u16)((hdB & 1) ? (sel0 >> 16) : (sel0 & 0xffffu)));
    float ae1v = h2f((u16)((hdB & 1) ? (sel1 >> 16) : (sel1 & 0xffffu)));
    float as0 = asrc[sc0 * 4 + hdB], as1 = asrc[sc1 * 4 + hdB];
    const uint4 row0 = *(const uint4*)(hp16 + (size_t)sc0 * 128 + cb);
    const uint4 row1 = *(const uint4*)(hp16 + (size_t)sc1 * 128 + cb);
    float l0 = as0 + advB + ae0; l0 = fmaxf(l0, 0.2f * l0);
    float l1 = as1 + advB + ae1v; l1 = fmaxf(l1, 0.2f * l1);
    float w0 = (i0 < s1) ? __expf(l0) : 0.f;
    float w1 = (i1 < s1) ? __expf(l1) : 0.f;
    ssp += w0 + w1;
    sap += ((i0 < s1) ? ae0 : 0.f) + ((i1 < s1) ? ae1v : 0.f);
    acc[0] += w0 * blo(row0.x) + w1 * blo(row1.x);
    acc[1] += w0 * bhi(row0.x) + w1 * bhi(row1.x);
    acc[2] += w0 * blo(row0.y) + w1 * blo(row1.y);
    acc[3] += w0 * bhi(row0.y) + w1 * bhi(row1.y);
    acc[4] += w0 * blo(row0.z) + w1 * blo(row1.z);
    acc[5] += w0 * bhi(row0.z) + w1 * bhi(row1.z);
    acc[6] += w0 * blo(row0.w) + w1 * blo(row1.w);
    acc[7] += w0 * bhi(row0.w) + w1 * bhi(row1.w);
    ra0 = nra0; rb0 = nrb0; ra1 = nra1; rb1 = nrb1;
  }
  // reduce across the 4 edge-groups
#pragma unroll
  for (int i = 0; i < 8; ++i) {
    acc[i] += __shfl_xor(acc[i], 16);
    acc[i] += __shfl_xor(acc[i], 32);
  }
  ssp += __shfl_xor(ssp, 16); ssp += __shfl_xor(ssp, 32);
  sap += __shfl_xor(sap, 16); sap += __shfl_xor(sap, 32);
  // self-loop (fill_value='mean' fold) + normalization
  const float degf = (float)(dg > 0 ? dg : 1);
  float asnB = asrc[n * 4 + hdB];
  float la = asnB + advB + sap / degf;
  la = fmaxf(la, 0.2f * la);
  float wsf = __expf(la);
  float inv = 1.f / (ssp + wsf + 1e-16f);
  // epilogue
  const uint4 rs4 = *(const uint4*)(hp16 + (size_t)n * 128 + cb);
  const uint4 rr4 = *(const uint4*)(feat16 + (size_t)n * 128 + cb);
  const float4 gb0 = *(const float4*)(gbias + cb);
  const float4 gb1 = *(const float4*)(gbias + cb + 4);
  float v[8];
  v[0] = (acc[0] + wsf * blo(rs4.x)) * inv + gb0.x + blo(rr4.x);
  v[1] = (acc[1] + wsf * bhi(rs4.x)) * inv + gb0.y + bhi(rr4.x);
  v[2] = (acc[2] + wsf * blo(rs4.y)) * inv + gb0.z + blo(rr4.y);
  v[3] = (acc[3] + wsf * bhi(rs4.y)) * inv + gb0.w + bhi(rr4.y);
  v[4] = (acc[4] + wsf * blo(rs4.z)) * inv + gb1.x + blo(rr4.z);
  v[5] = (acc[5] + wsf * bhi(rs4.z)) * inv + gb1.y + bhi(rr4.z);
  v[6] = (acc[6] + wsf * blo(rs4.w)) * inv + gb1.z + blo(rr4.w);
  v[7] = (acc[7] + wsf * bhi(rs4.w)) * inv + gb1.w + bhi(rr4.w);
  float sum = 0.f, sq = 0.f;
#pragma unroll
  for (int i = 0; i < 8; ++i) {
    v[i] = fminf(fmaxf(v[i], -10.f), 10.f);
    sum += v[i]; sq += v[i] * v[i];
  }
#pragma unroll
  for (int o = 1; o < 16; o <<= 1) {
    sum += __shfl_xor(sum, o);
    sq += __shfl_xor(sq, o);
  }
  float mu = sum * (1.f / 128.f);
  float var = sq * (1.f / 128.f) - mu * mu;
  float rstd = rsqrtf(var + 1e-5f);
  const float4 lw0 = *(const float4*)(lnw + cb);
  const float4 lw1 = *(const float4*)(lnw + cb + 4);
  const float4 lb0 = *(const float4*)(lnb + cb);
  const float4 lb1 = *(const float4*)(lnb + cb + 4);
  float y[8];
  y[0] = (v[0] - mu) * rstd * lw0.x + lb0.x;
  y[1] = (v[1] - mu) * rstd * lw0.y + lb0.y;
  y[2] = (v[2] - mu) * rstd * lw0.z + lb0.z;
  y[3] = (v[3] - mu) * rstd * lw0.w + lb0.w;
  y[4] = (v[4] - mu) * rstd * lw1.x + lb1.x;
  y[5] = (v[5] - mu) * rstd * lw1.y + lb1.y;
  y[6] = (v[6] - mu) * rstd * lw1.z + lb1.z;
  y[7] = (v[7] - mu) * rstd * lw1.w + lb1.w;
#pragma unroll
  for (int i = 0; i < 8; ++i) y[i] = y[i] > 0.f ? y[i] : expm1f(y[i]);
  if (g == 0) {
    if (FINAL) {
      float4 o0 = {y[0], y[1], y[2], y[3]};
      float4 o1 = {y[4], y[5], y[6], y[7]};
      *(float4*)(out32 + (size_t)n * 128 + cb) = o0;
      *(float4*)(out32 + (size_t)n * 128 + cb + 4) = o1;
    } else {
      uint4 o;
      o.x = (unsigned)f2b(y[0]) | ((unsigned)f2b(y[1]) << 16);
      o.y = (unsigned)f2b(y[2]) | ((unsigned)f2b(y[3]) << 16);
      o.z = (unsigned)f2b(y[4]) | ((unsigned)f2b(y[5]) << 16);
      o.w = (unsigned)f2b(y[6]) | ((unsigned)f2b(y[7]) << 16);
      *(uint4*)(gout16 + (size_t)n * 128 + cb) = o;
    }
  }
}

// ---------- launch ----------
extern "C" void kernel_launch(void* const* d_in, const int* in_sizes, int n_in,
                              void* d_out, int out_size, void* d_ws, size_t ws_size,
                              hipStream_t stream) {
  const float* x      = (const float*)d_in[0];
  const float* etime  = (const float*)d_in[1];
  const float* ip_w1  = (const float*)d_in[2];
  const float* ip_b1  = (const float*)d_in[3];
  const float* ip_lnw = (const float*)d_in[4];
  const float* ip_lnb = (const float*)d_in[5];
  const float* ip_w2  = (const float*)d_in[6];
  const float* ip_b2  = (const float*)d_in[7];
  const float* pn_w   = (const float*)d_in[8];
  const float* pn_b   = (const float*)d_in[9];
  const float* ta_w1  = (const float*)d_in[10];
  const float* ta_b1  = (const float*)d_in[11];
  const float* ta_lnw = (const float*)d_in[12];
  const float* ta_lnb = (const float*)d_in[13];
  const float* ta_w2  = (const float*)d_in[14];
  const float* ta_b2  = (const float*)d_in[15];
  const float* g1_w   = (const float*)d_in[16];
  const float* g1_as  = (const float*)d_in[17];
  const float* g1_ad  = (const float*)d_in[18];
  const float* g1_ew  = (const float*)d_in[19];
  const float* g1_ae  = (const float*)d_in[20];
  const float* g1_b   = (const float*)d_in[21];
  const float* g2_w   = (const float*)d_in[22];
  const float* g2_as  = (const float*)d_in[23];
  const float* g2_ad  = (const float*)d_in[24];
  const float* g2_ew  = (const float*)d_in[25];
  const float* g2_ae  = (const float*)d_in[26];
  const float* g2_b   = (const float*)d_in[27];
  const float* n1_w   = (const float*)d_in[28];
  const float* n1_b   = (const float*)d_in[29];
  const float* n2_w   = (const float*)d_in[30];
  const float* n2_b   = (const float*)d_in[31];
  const int* eidx     = (const int*)d_in[32];
  const int* srcv = eidx;
  const int* dstv = eidx + NE;

  char* p = (char*)d_ws;
  auto carve = [&](size_t bytes) -> char* {
    char* r = p;
    p += (bytes + 255) & ~(size_t)255;
    return r;
  };
  u16*   h16    = (u16*)carve((size_t)NN * 128 * 2);
  u16*   g16    = (u16*)carve((size_t)NN * 128 * 2);
  u16*   hp16   = (u16*)carve((size_t)NN * 128 * 2);
  float* asrc   = (float*)carve((size_t)NN * 4 * 4);
  float* adst   = (float*)carve((size_t)NN * 4 * 4);
  u16*   recs   = (u16*)carve((size_t)NE * 32);
  int*   deg    = (int*)carve((size_t)NN * 4);
  int*   indptr = (int*)carve((size_t)(NN + 1) * 4);
  int*   cursor = (int*)carve((size_t)NN * 4);
  int*   blks   = (int*)carve(512 * 4);
  float* tbl    = (float*)carve((size_t)TBLN * 8 * 4);
  u16*   w1t    = (u16*)carve(128 * 256 * 2);
  u16*   w2t    = (u16*)carve(256 * 128 * 2);
  u16*   g1wt   = (u16*)carve(128 * 128 * 2);
  u16*   g2wt   = (u16*)carve(128 * 128 * 2);
  // x16 aliases g16: x16 written in prep_k, last read in fillip_k's GEMM1;
  // g16 first written by agg_k<0>, which launches after fillip. Stream-serialized.
  u16*   x16    = (u16*)g16;

  hipMemsetAsync(deg, 0, (size_t)NN * 4, stream);

  const int SCB = (NN + 511) / 512;  // 98

  // transposes + histogram + x16 + a_edge table, one launch
  prep_k<<<384 + 2 * FB + TBB, 256, 0, stream>>>(
      g1_ew, g1_ae, g2_ew, g2_ae,
      ip_w1, ip_w2, g1_w, g2_w,
      w1t, w2t, g1wt, g2wt, dstv, deg,
      x, x16,
      ta_w1, ta_b1, ta_lnw, ta_lnb, ta_w2, ta_b2, tbl);
  scan1<<<SCB, 512, 0, stream>>>(deg, indptr, blks);
  scan23<<<SCB, 512, 0, stream>>>(indptr, blks, deg, cursor, SCB);
  // fill + {ip GEMM1/2 + fused hp1 GEMM3} -> h16, hp16, asrc, adst, recs
  fillip_k<<<MB64 + FB, 256, 0, stream>>>(srcv, dstv, etime, tbl, cursor, recs,
                                          x16, w1t, ip_b1, ip_lnw, ip_lnb, w2t, ip_b2,
                                          pn_w, pn_b, h16,
                                          g1wt, g1_as, g1_ad, hp16, asrc, adst);
  // agg layer 1
  agg_k<0, 0><<<NN / 4, 256, 0, stream>>>(indptr, recs, asrc, adst, hp16, h16,
                                          g1_b, n1_w, n1_b, g16, nullptr);
  // layer-2 projection
  hp_mfma<<<MB64, 256, 0, stream>>>(g16, g2wt, g2_as, g2_ad, hp16, asrc, adst);
  // agg layer 2 (final)
  agg_k<1, 1><<<NN / 4, 256, 0, stream>>>(indptr, recs, asrc, adst, hp16, g16,
                                          g2_b, n2_w, n2_b, nullptr, (float*)d_out);
}

// Round 10
// 384.626 us; speedup vs baseline: 1.2636x; 1.2636x over previous
//
#include <hip/hip_runtime.h>

typedef unsigned short u16;
typedef __attribute__((ext_vector_type(8))) short bf8_t;   // 8 bf16 in 4 VGPRs
typedef __attribute__((ext_vector_type(4))) float f4_t;

constexpr int NN   = 50000;
constexpr int NE   = 800000;
constexpr int TBLN = 2048;
constexpr int MB64 = (NN + 63) / 64;  // 782 ip blocks (64-row tiles)
constexpr int FB   = NE / 256;        // 3125 fill blocks

// ---------- helpers ----------
__device__ __forceinline__ u16 f2b(float f) {
  unsigned u = __float_as_uint(f);
  unsigned r = u + 0x7fffu + ((u >> 16) & 1u);  // RNE
  return (u16)(r >> 16);
}
__device__ __forceinline__ u16 f2h(float f) {
  _Float16 h = (_Float16)f;
  return __builtin_bit_cast(unsigned short, h);
}
__device__ __forceinline__ float h2f(u16 v) {
  _Float16 h = __builtin_bit_cast(_Float16, v);
  return (float)h;
}
__device__ __forceinline__ unsigned packh(float a, float b) {
  return (unsigned)f2h(a) | ((unsigned)f2h(b) << 16);
}
__device__ __forceinline__ float blo(unsigned u) { return __uint_as_float(u << 16); }
__device__ __forceinline__ float bhi(unsigned u) { return __uint_as_float(u & 0xffff0000u); }
__device__ __forceinline__ float wred64(float v) {
#pragma unroll
  for (int o = 32; o; o >>= 1) v += __shfl_xor(v, o);
  return v;
}
__device__ __forceinline__ int iwred64(int v) {
#pragma unroll
  for (int o = 32; o; o >>= 1) v += __shfl_xor(v, o);
  return v;
}
__device__ __forceinline__ bf8_t ldv(const u16* p) { return *(const bf8_t*)p; }
__device__ __forceinline__ f4_t mfma16(bf8_t a, bf8_t b, f4_t c) {
  return __builtin_amdgcn_mfma_f32_16x16x32_bf16(a, b, c, 0, 0, 0);
}

// ---------- prep: build_V + weight transposes + deg histogram + x->bf16 ----------
__global__ __launch_bounds__(256) void prep_k(
    const float* __restrict__ ew1, const float* __restrict__ ate1,
    const float* __restrict__ ew2, const float* __restrict__ ate2,
    float* __restrict__ V,
    const float* __restrict__ w1, const float* __restrict__ w2,
    const float* __restrict__ gw1, const float* __restrict__ gw2,
    u16* __restrict__ w1t, u16* __restrict__ w2t,
    u16* __restrict__ g1wt, u16* __restrict__ g2wt,
    const int* __restrict__ dstv, int* __restrict__ deg,
    const float* __restrict__ x, u16* __restrict__ x16) {
  const int bid = blockIdx.x, t = threadIdx.x;
  if (bid == 0) {
#pragma unroll
    for (int rep = 0; rep < 2; ++rep) {
      int idx = t + rep * 256;
      int k = idx >> 2, hd = idx & 3;
      float s1 = 0.f, s2 = 0.f;
      for (int c = 0; c < 32; ++c) {
        s1 += ew1[k * 128 + hd * 32 + c] * ate1[hd * 32 + c];
        s2 += ew2[k * 128 + hd * 32 + c] * ate2[hd * 32 + c];
      }
      V[k * 8 + hd] = s1;
      V[k * 8 + 4 + hd] = s2;
    }
  } else if (bid <= 384) {
    int idx = (bid - 1) * 256 + t;
    if (idx < 32768) {
      int r = idx >> 8, c = idx & 255;
      w1t[c * 128 + r] = f2b(w1[idx]);
    } else if (idx < 65536) {
      int k = idx - 32768;
      int r = k >> 7, c = k & 127;
      w2t[c * 256 + r] = f2b(w2[k]);
    } else if (idx < 81920) {
      int k = idx - 65536;
      int r = k >> 7, c = k & 127;
      g1wt[c * 128 + r] = f2b(gw1[k]);
    } else {
      int k = idx - 81920;
      int r = k >> 7, c = k & 127;
      g2wt[c * 128 + r] = f2b(gw2[k]);
    }
  } else if (bid <= 384 + FB) {
    int e = (bid - 385) * 256 + t;
    if (e < NE) atomicAdd(&deg[dstv[e]], 1);
  } else {
    // x (fp32) -> x16 (bf16), 8 elems/thread, exact grid (3125 blocks)
    int idx = (bid - 385 - FB) * 256 + t;
    size_t e8 = (size_t)idx * 8;
    const float4 a = *(const float4*)(x + e8);
    const float4 b = *(const float4*)(x + e8 + 4);
    uint4 o;
    o.x = (unsigned)f2b(a.x) | ((unsigned)f2b(a.y) << 16);
    o.y = (unsigned)f2b(a.z) | ((unsigned)f2b(a.w) << 16);
    o.z = (unsigned)f2b(b.x) | ((unsigned)f2b(b.y) << 16);
    o.w = (unsigned)f2b(b.z) | ((unsigned)f2b(b.w) << 16);
    *(uint4*)(x16 + e8) = o;
  }
}

// ---------- tabulate a_edge(t), row-major tbl[TBLN][8] ----------
__global__ __launch_bounds__(128) void build_table(
    const float* __restrict__ taw1, const float* __restrict__ tab1,
    const float* __restrict__ talnw, const float* __restrict__ talnb,
    const float* __restrict__ taw2, const float* __restrict__ tab2,
    const float* __restrict__ V, float* __restrict__ tbl) {
  const int j = threadIdx.x;
  const int wv = j >> 6, ln = j & 63;
  const float t = (float)blockIdx.x / (float)(TBLN - 1);
  __shared__ float part[4];
  __shared__ float ush[128];
  __shared__ float pacc[16];
  float v = t * taw1[j] + tab1[j];
  float s = wred64(v), sq = wred64(v * v);
  if (ln == 0) { part[wv * 2] = s; part[wv * 2 + 1] = sq; }
  __syncthreads();
  float S = part[0] + part[2], SQ = part[1] + part[3];
  float mu = S * (1.f / 128.f);
  float var = SQ * (1.f / 128.f) - mu * mu;
  float rstd = rsqrtf(var + 1e-5f);
  float u = fmaxf((v - mu) * rstd * talnw[j] + talnb[j], 0.f);
  ush[j] = u;
  __syncthreads();
  float acc = 0.f;
  for (int k = 0; k < 128; ++k) acc += ush[k] * taw2[k * 128 + j];
  float w = tanhf(acc + tab2[j]);
  w = fminf(fmaxf(w, -3.f), 3.f);
#pragma unroll
  for (int p = 0; p < 8; ++p) {
    float z = wred64(w * V[j * 8 + p]);
    if (ln == 0) pacc[wv * 8 + p] = z;
  }
  __syncthreads();
  if (j < 8) tbl[blockIdx.x * 8 + j] = pacc[j] + pacc[8 + j];
}

// ---------- scans ----------
__global__ __launch_bounds__(512) void scan1(const int* __restrict__ deg,
                                             int* __restrict__ indptr,
                                             int* __restrict__ blks) {
  const int t = threadIdx.x;
  const int i = blockIdx.x * 512 + t;
  int v = (i < NN) ? deg[i] : 0;
  const int lane = t & 63, wv = t >> 6;
  int x = v;
#pragma unroll
  for (int o = 1; o < 64; o <<= 1) {
    int y = __shfl_up(x, o);
    if (lane >= o) x += y;
  }
  __shared__ int ws[8];
  if (lane == 63) ws[wv] = x;
  __syncthreads();
  if (t < 8) {
    int y = ws[t];
#pragma unroll
    for (int o = 1; o < 8; o <<= 1) {
      int z = __shfl_up(y, o);
      if (t >= o) y += z;
    }
    ws[t] = y;
  }
  __syncthreads();
  int excl = wv ? ws[wv - 1] : 0;
  x += excl;
  if (i < NN) indptr[i + 1] = x;
  if (t == 511) blks[blockIdx.x] = x;
}
// scan23: fuses scan2 (block-offset scan, redundantly per block as a sum of
// preceding block totals) + scan3 (apply offsets, seed cursor).
__global__ __launch_bounds__(512) void scan23(int* __restrict__ indptr,
                                              const int* __restrict__ blks,
                                              const int* __restrict__ deg,
                                              int* __restrict__ cursor, int nb) {
  const int t = threadIdx.x;
  int v = (t < nb && t < blockIdx.x) ? blks[t] : 0;
  const int wv = t >> 6;
  int x = iwred64(v);
  __shared__ int ws[8];
  if ((t & 63) == 0) ws[wv] = x;
  __syncthreads();
  int prefix = ws[0] + ws[1] + ws[2] + ws[3] + ws[4] + ws[5] + ws[6] + ws[7];
  const int i = blockIdx.x * 512 + t;
  if (i < NN) {
    int val = indptr[i + 1] + prefix;
    indptr[i + 1] = val;
    cursor[i] = val - deg[i];
  }
  if (i == 0) indptr[0] = 0;
}

// ---------- CSR fill body (lerp + 20B record); zero LDS use ----------
__device__ void fill_body(int fb, const int* __restrict__ srcv,
                          const int* __restrict__ dstv,
                          const float* __restrict__ etime,
                          const float* __restrict__ tbl,
                          int* __restrict__ cursor,
                          u16* __restrict__ recs) {
  const int e = fb * 256 + threadIdx.x;
  if (e >= NE) return;
  int d = dstv[e];
  int pos = atomicAdd(&cursor[d], 1);
  float t = etime[e];
  t = fminf(fmaxf(t, 0.f), 1.f);
  float fpos = t * (float)(TBLN - 1);
  int i0 = (int)fpos;
  if (i0 > TBLN - 2) i0 = TBLN - 2;
  float fr = fpos - (float)i0;
  const float4* r = (const float4*)(tbl + i0 * 8);
  float4 a0 = r[0], a1 = r[1], b0 = r[2], b1 = r[3];
  float4 o1, o2;
  o1.x = a0.x + fr * (b0.x - a0.x); o1.y = a0.y + fr * (b0.y - a0.y);
  o1.z = a0.z + fr * (b0.z - a0.z); o1.w = a0.w + fr * (b0.w - a0.w);
  o2.x = a1.x + fr * (b1.x - a1.x); o2.y = a1.y + fr * (b1.y - a1.y);
  o2.z = a1.z + fr * (b1.z - a1.z); o2.w = a1.w + fr * (b1.w - a1.w);
  u16* rp = recs + (size_t)pos * 16;
  uint4 w;
  w.x = (unsigned)srcv[e];
  w.y = packh(o1.x, o1.y);
  w.z = packh(o1.z, o1.w);
  w.w = packh(o2.x, o2.y);
  *(uint4*)rp = w;
  *(unsigned*)(rp + 8) = packh(o2.z, o2.w);
}

// 64-row register-LN input projection + fused hp1 (GEMM3 from LDS).
// LDS: h1n[64][264] bf16 (h2n[64][136] aliased) + partS/partQ [4][64] f32
__device__ void ip_body(int ipb, char* smem,
                        const u16* __restrict__ x16, const u16* __restrict__ w1t,
                        const float* __restrict__ b1, const float* __restrict__ ln1w,
                        const float* __restrict__ ln1b, const u16* __restrict__ w2t,
                        const float* __restrict__ b2, const float* __restrict__ pnw,
                        const float* __restrict__ pnb, u16* __restrict__ h16,
                        const u16* __restrict__ g1wt, const float* __restrict__ attsrc,
                        const float* __restrict__ attdst, u16* __restrict__ hp16,
                        float* __restrict__ asrc, float* __restrict__ adst) {
  u16* h1n = (u16*)smem;                        // [64][264] bf16
  u16* h2n = h1n;                               // alias, [64][136] after GEMM2
  float* partS = (float*)(smem + 33792);        // [4][64]
  float* partQ = (float*)(smem + 33792 + 1024); // [4][64]

  const int t = threadIdx.x;
  const int w = t >> 6, lane = t & 63, q = lane >> 4, l15 = lane & 15;
  const int rowbase = ipb * 64;

  // ---- GEMM1: [64,128] @ [128,256] ----
  f4_t acc[4][4];
#pragma unroll
  for (int mt = 0; mt < 4; ++mt)
#pragma unroll
    for (int nt = 0; nt < 4; ++nt) acc[mt][nt] = (f4_t){0.f, 0.f, 0.f, 0.f};
#pragma unroll
  for (int kst = 0; kst < 4; ++kst) {
    int k0 = kst * 32 + q * 8;
    bf8_t a[4];
#pragma unroll
    for (int mt = 0; mt < 4; ++mt) {
      int r = rowbase + mt * 16 + l15;
      if (r > NN - 1) r = NN - 1;
      a[mt] = ldv(x16 + (size_t)r * 128 + k0);
    }
#pragma unroll
    for (int nt = 0; nt < 4; ++nt) {
      int n = w * 64 + nt * 16 + l15;
      bf8_t b = ldv(w1t + n * 128 + k0);
#pragma unroll
      for (int mt = 0; mt < 4; ++mt)
        acc[mt][nt] = mfma16(a[mt], b, acc[mt][nt]);
    }
  }
  // bias + relu in regs
#pragma unroll
  for (int nt = 0; nt < 4; ++nt) {
    float bb = b1[w * 64 + nt * 16 + l15];
#pragma unroll
    for (int mt = 0; mt < 4; ++mt)
#pragma unroll
      for (int r = 0; r < 4; ++r)
        acc[mt][nt][r] = fmaxf(acc[mt][nt][r] + bb, 0.f);
  }
  // per-(mt,r) partial row sums over this wave's 64 cols
  {
    float s[4][4], sq[4][4];
#pragma unroll
    for (int mt = 0; mt < 4; ++mt)
#pragma unroll
      for (int r = 0; r < 4; ++r) {
        float a0 = acc[mt][0][r], b0 = acc[mt][1][r], c0 = acc[mt][2][r], d0 = acc[mt][3][r];
        s[mt][r] = a0 + b0 + c0 + d0;
        sq[mt][r] = a0 * a0 + b0 * b0 + c0 * c0 + d0 * d0;
      }
#pragma unroll
    for (int o = 1; o < 16; o <<= 1)
#pragma unroll
      for (int mt = 0; mt < 4; ++mt)
#pragma unroll
        for (int r = 0; r < 4; ++r) {
          s[mt][r] += __shfl_xor(s[mt][r], o);
          sq[mt][r] += __shfl_xor(sq[mt][r], o);
        }
    if (l15 == 0) {
#pragma unroll
      for (int mt = 0; mt < 4; ++mt)
#pragma unroll
        for (int r = 0; r < 4; ++r) {
          int row = mt * 16 + q * 4 + r;
          partS[w * 64 + row] = s[mt][r];
          partQ[w * 64 + row] = sq[mt][r];
        }
    }
  }
  __syncthreads();
  // LN1 from registers -> h1n (bf16)
  {
    float lw[4], lb[4];
#pragma unroll
    for (int nt = 0; nt < 4; ++nt) {
      int col = w * 64 + nt * 16 + l15;
      lw[nt] = ln1w[col]; lb[nt] = ln1b[col];
    }
#pragma unroll
    for (int mt = 0; mt < 4; ++mt)
#pragma unroll
      for (int r = 0; r < 4; ++r) {
        int row = mt * 16 + q * 4 + r;
        float S = partS[row] + partS[64 + row] + partS[128 + row] + partS[192 + row];
        float Q = partQ[row] + partQ[64 + row] + partQ[128 + row] + partQ[192 + row];
        float mu = S * (1.f / 256.f);
        float var = Q * (1.f / 256.f) - mu * mu;
        float rstd = rsqrtf(var + 1e-5f);
#pragma unroll
        for (int nt = 0; nt < 4; ++nt) {
          int col = w * 64 + nt * 16 + l15;
          h1n[row * 264 + col] = f2b((acc[mt][nt][r] - mu) * rstd * lw[nt] + lb[nt]);
        }
      }
  }
  __syncthreads();
  // ---- GEMM2: [64,256] @ [256,128] ----
  f4_t acc2[4][2];
#pragma unroll
  for (int mt = 0; mt < 4; ++mt)
#pragma unroll
    for (int nt = 0; nt < 2; ++nt) acc2[mt][nt] = (f4_t){0.f, 0.f, 0.f, 0.f};
#pragma unroll
  for (int kst = 0; kst < 8; ++kst) {
    int k0 = kst * 32 + q * 8;
    bf8_t a[4];
#pragma unroll
    for (int mt = 0; mt < 4; ++mt)
      a[mt] = ldv(h1n + (mt * 16 + l15) * 264 + k0);
#pragma unroll
    for (int nt = 0; nt < 2; ++nt) {
      int n = w * 32 + nt * 16 + l15;
      bf8_t b = ldv(w2t + n * 256 + k0);
#pragma unroll
      for (int mt = 0; mt < 4; ++mt)
        acc2[mt][nt] = mfma16(a[mt], b, acc2[mt][nt]);
    }
  }
  // bias in regs, partial sums
#pragma unroll
  for (int nt = 0; nt < 2; ++nt) {
    float bb = b2[w * 32 + nt * 16 + l15];
#pragma unroll
    for (int mt = 0; mt < 4; ++mt)
#pragma unroll
      for (int r = 0; r < 4; ++r)
        acc2[mt][nt][r] += bb;
  }
  {
    float s[4][4], sq[4][4];
#pragma unroll
    for (int mt = 0; mt < 4; ++mt)
#pragma unroll
      for (int r = 0; r < 4; ++r) {
        float a0 = acc2[mt][0][r], b0 = acc2[mt][1][r];
        s[mt][r] = a0 + b0;
        sq[mt][r] = a0 * a0 + b0 * b0;
      }
#pragma unroll
    for (int o = 1; o < 16; o <<= 1)
#pragma unroll
      for (int mt = 0; mt < 4; ++mt)
#pragma unroll
        for (int r = 0; r < 4; ++r) {
          s[mt][r] += __shfl_xor(s[mt][r], o);
          sq[mt][r] += __shfl_xor(sq[mt][r], o);
        }
    __syncthreads();  // all GEMM2 h1n reads done
    if (l15 == 0) {
#pragma unroll
      for (int mt = 0; mt < 4; ++mt)
#pragma unroll
        for (int r = 0; r < 4; ++r) {
          int row = mt * 16 + q * 4 + r;
          partS[w * 64 + row] = s[mt][r];
          partQ[w * 64 + row] = sq[mt][r];
        }
    }
  }
  __syncthreads();
  // LN2 + relu + clip -> h2n[64][136] (aliased on h1n; safe after sync)
  {
    float lw[2], lb[2];
#pragma unroll
    for (int nt = 0; nt < 2; ++nt) {
      int col = w * 32 + nt * 16 + l15;
      lw[nt] = pnw[col]; lb[nt] = pnb[col];
    }
#pragma unroll
    for (int mt = 0; mt < 4; ++mt)
#pragma unroll
      for (int r = 0; r < 4; ++r) {
        int row = mt * 16 + q * 4 + r;
        float S = partS[row] + partS[64 + row] + partS[128 + row] + partS[192 + row];
        float Q = partQ[row] + partQ[64 + row] + partQ[128 + row] + partQ[192 + row];
        float mu = S * (1.f / 128.f);
        float var = Q * (1.f / 128.f) - mu * mu;
        float rstd = rsqrtf(var + 1e-5f);
#pragma unroll
        for (int nt = 0; nt < 2; ++nt) {
          int col = w * 32 + nt * 16 + l15;
          float v = (acc2[mt][nt][r] - mu) * rstd * lw[nt] + lb[nt];
          v = fminf(fmaxf(v, 0.f), 10.f);
          h2n[row * 136 + col] = f2b(v);
        }
      }
  }
  __syncthreads();
  // coalesced h16 stores: 64 rows x 128 cols bf16
  {
    const int row = t >> 2, cb = (t & 3) * 32;
    int rg = rowbase + row;
    if (rg < NN) {
#pragma unroll
      for (int c = 0; c < 4; ++c) {
        uint4 v0 = *(const uint4*)(h2n + row * 136 + cb + c * 8);
        *(uint4*)(h16 + (size_t)rg * 128 + cb + c * 8) = v0;
      }
    }
  }
  // ---- GEMM3 (fused hp1): [64,128] @ [128,128] -> hp16, asrc, adst ----
  f4_t acc3[4][2];
#pragma unroll
  for (int mt = 0; mt < 4; ++mt)
#pragma unroll
    for (int nt = 0; nt < 2; ++nt) acc3[mt][nt] = (f4_t){0.f, 0.f, 0.f, 0.f};
#pragma unroll
  for (int kst = 0; kst < 4; ++kst) {
    int k0 = kst * 32 + q * 8;
    bf8_t a[4];
#pragma unroll
    for (int mt = 0; mt < 4; ++mt)
      a[mt] = ldv(h2n + (mt * 16 + l15) * 136 + k0);
#pragma unroll
    for (int nt = 0; nt < 2; ++nt) {
      int n = w * 32 + nt * 16 + l15;
      bf8_t b = ldv(g1wt + n * 128 + k0);
#pragma unroll
      for (int mt = 0; mt < 4; ++mt)
        acc3[mt][nt] = mfma16(a[mt], b, acc3[mt][nt]);
    }
  }
  {
    float ps[4][4], pd[4][4];
#pragma unroll
    for (int mt = 0; mt < 4; ++mt)
#pragma unroll
      for (int r = 0; r < 4; ++r) { ps[mt][r] = 0.f; pd[mt][r] = 0.f; }
#pragma unroll
    for (int mt = 0; mt < 4; ++mt)
#pragma unroll
      for (int nt = 0; nt < 2; ++nt) {
        int col = w * 32 + nt * 16 + l15;
        float as = attsrc[col], ad = attdst[col];
#pragma unroll
        for (int r = 0; r < 4; ++r) {
          int row = mt * 16 + q * 4 + r;
          int rg = rowbase + row;
          float v = acc3[mt][nt][r];
          if (rg < NN) hp16[(size_t)rg * 128 + col] = f2b(v);
          ps[mt][r] += v * as;
          pd[mt][r] += v * ad;
        }
      }
#pragma unroll
    for (int o = 1; o < 16; o <<= 1)
#pragma unroll
      for (int mt = 0; mt < 4; ++mt)
#pragma unroll
        for (int r = 0; r < 4; ++r) {
          ps[mt][r] += __shfl_xor(ps[mt][r], o);
          pd[mt][r] += __shfl_xor(pd[mt][r], o);
        }
    if (l15 == 0) {
#pragma unroll
      for (int mt = 0; mt < 4; ++mt)
#pragma unroll
        for (int r = 0; r < 4; ++r) {
          int rg = rowbase + mt * 16 + q * 4 + r;
          if (rg < NN) {
            asrc[rg * 4 + w] = ps[mt][r];
            adst[rg * 4 + w] = pd[mt][r];
          }
        }
    }
  }
}

__global__ __launch_bounds__(256) void fillip_k(
    const int* srcv, const int* dstv, const float* etime, const float* tbl,
    int* cursor, u16* recs,
    const u16* x16, const u16* w1t, const float* b1, const float* ln1w,
    const float* ln1b, const u16* w2t, const float* b2, const float* pnw,
    const float* pnb, u16* h16,
    const u16* g1wt, const float* g1as, const float* g1ad,
    u16* hp16, float* asrc, float* adst) {
  __shared__ char smem[35840];
  const int bid = blockIdx.x;
  if (bid % 5 == 0) {
    ip_body(bid / 5, smem, x16, w1t, b1, ln1w, ln1b, w2t, b2, pnw, pnb, h16,
            g1wt, g1as, g1ad, hp16, asrc, adst);
  } else {
    fill_body(bid - bid / 5 - 1, srcv, dstv, etime, tbl, cursor, recs);
  }
}

// ---------- standalone hp (layer 2): node projection + attention logits ----------
__global__ __launch_bounds__(256) void hp_mfma(
    const u16* __restrict__ feat16, const u16* __restrict__ wt,
    const float* __restrict__ attsrc, const float* __restrict__ attdst,
    u16* __restrict__ hp16, float* __restrict__ asrc, float* __restrict__ adst) {
  const int t = threadIdx.x;
  const int w = t >> 6, lane = t & 63, q = lane >> 4, l15 = lane & 15;
  const int rowbase = blockIdx.x * 64;
  f4_t acc[4][2];
#pragma unroll
  for (int mt = 0; mt < 4; ++mt)
#pragma unroll
    for (int nt = 0; nt < 2; ++nt) acc[mt][nt] = (f4_t){0.f, 0.f, 0.f, 0.f};
#pragma unroll
  for (int kst = 0; kst < 4; ++kst) {
    int k0 = kst * 32 + q * 8;
    bf8_t a[4];
#pragma unroll
    for (int mt = 0; mt < 4; ++mt) {
      int r = rowbase + mt * 16 + l15;
      if (r > NN - 1) r = NN - 1;
      a[mt] = ldv(feat16 + (size_t)r * 128 + k0);
    }
#pragma unroll
    for (int nt = 0; nt < 2; ++nt) {
      int n = w * 32 + nt * 16 + l15;
      bf8_t b = ldv(wt + n * 128 + k0);
#pragma unroll
      for (int mt = 0; mt < 4; ++mt)
        acc[mt][nt] = mfma16(a[mt], b, acc[mt][nt]);
    }
  }
  float ps[4][4], pd[4][4];
#pragma unroll
  for (int mt = 0; mt < 4; ++mt)
#pragma unroll
    for (int r = 0; r < 4; ++r) { ps[mt][r] = 0.f; pd[mt][r] = 0.f; }
#pragma unroll
  for (int mt = 0; mt < 4; ++mt)
#pragma unroll
    for (int nt = 0; nt < 2; ++nt) {
      int col = w * 32 + nt * 16 + l15;
      float as = attsrc[col], ad = attdst[col];
#pragma unroll
      for (int r = 0; r < 4; ++r) {
        int row = mt * 16 + q * 4 + r;
        int rg = rowbase + row;
        float v = acc[mt][nt][r];
        if (rg < NN) hp16[(size_t)rg * 128 + col] = f2b(v);
        ps[mt][r] += v * as;
        pd[mt][r] += v * ad;
      }
    }
#pragma unroll
  for (int o = 1; o < 16; o <<= 1)
#pragma unroll
    for (int mt = 0; mt < 4; ++mt)
#pragma unroll
      for (int r = 0; r < 4; ++r) {
        ps[mt][r] += __shfl_xor(ps[mt][r], o);
        pd[mt][r] += __shfl_xor(pd[mt][r], o);
      }
  if (l15 == 0) {
#pragma unroll
    for (int mt = 0; mt < 4; ++mt)
#pragma unroll
      for (int r = 0; r < 4; ++r) {
        int rg = rowbase + mt * 16 + q * 4 + r;
        if (rg < NN) {
          asrc[rg * 4 + w] = ps[mt][r];
          adst[rg * 4 + w] = pd[mt][r];
        }
      }
  }
}

// ---------- GAT aggregation: 1-deep record prefetch pipeline ----------
template <int L, int FINAL>
__global__ __launch_bounds__(256) void agg_k(
    const int* __restrict__ indptr, const u16* __restrict__ recs,
    const float* __restrict__ asrc, const float* __restrict__ adst,
    const u16* __restrict__ hp16, const u16* __restrict__ feat16,
    const float* __restrict__ gbias, const float* __restrict__ lnw,
    const float* __restrict__ lnb, u16* __restrict__ gout16,
    float* __restrict__ out32) {
  const int wv = threadIdx.x >> 6, lane = threadIdx.x & 63;
  const int n = blockIdx.x * 4 + wv;
  if (n >= NN) return;
  const int s0 = indptr[n], s1 = indptr[n + 1];
  const int dg = s1 - s0;
  const int g = lane >> 4, sl = lane & 15, cb = sl * 8, hdB = sl >> 2;
  const float advB = adst[n * 4 + hdB];
  float ssp = 0.f, sap = 0.f;
  float acc[8];
#pragma unroll
  for (int i = 0; i < 8; ++i) acc[i] = 0.f;
  const int s1m1 = s1 - 1;
  // preload first iteration's records
  int pi0 = s0 + g, pi1 = s0 + 4 + g;
  int pj0 = pi0 < s1 ? pi0 : s1m1, pj1 = pi1 < s1 ? pi1 : s1m1;
  uint4 ra0 = *(const uint4*)(recs + (size_t)pj0 * 16);
  unsigned rb0 = *(const unsigned*)(recs + (size_t)pj0 * 16 + 8);
  uint4 ra1 = *(const uint4*)(recs + (size_t)pj1 * 16);
  unsigned rb1 = *(const unsigned*)(recs + (size_t)pj1 * 16 + 8);
  for (int base = s0; base < s1; base += 8) {
    // issue next iteration's record loads before the dependent row gathers
    uint4 nra0 = ra0, nra1 = ra1;
    unsigned nrb0 = rb0, nrb1 = rb1;
    int nbase = base + 8;
    if (nbase < s1) {
      int ni0 = nbase + g, ni1 = nbase + 4 + g;
      int nj0 = ni0 < s1 ? ni0 : s1m1, nj1 = ni1 < s1 ? ni1 : s1m1;
      nra0 = *(const uint4*)(recs + (size_t)nj0 * 16);
      nrb0 = *(const unsigned*)(recs + (size_t)nj0 * 16 + 8);
      nra1 = *(const uint4*)(recs + (size_t)nj1 * 16);
      nrb1 = *(const unsigned*)(recs + (size_t)nj1 * 16 + 8);
    }
    int i0 = base + g, i1 = base + 4 + g;
    int sc0 = (int)ra0.x, sc1 = (int)ra1.x;
    // attr extraction: u16 index 2+4L+hdB
    //  L0: words {ra.y (u16 2,3), ra.z (u16 4,5)};  L1: {ra.w (u16 6,7), rb (u16 8,9)}
    unsigned w00, w01, w10, w11;
    if (L == 0) { w00 = ra0.y; w01 = ra0.z; w10 = ra1.y; w11 = ra1.z; }
    else        { w00 = ra0.w; w01 = rb0;   w10 = ra1.w; w11 = rb1; }
    unsigned sel0 = (hdB & 2) ? w01 : w00;
    unsigned sel1 = (hdB & 2) ? w11 : w10;
    float ae0 = h2f((u16)((hdB & 1) ? (sel0 >> 16) : (sel0 & 0xffffu)));
    float ae1v = h2f((u16)((hdB & 1) ? (sel1 >> 16) : (sel1 & 0xffffu)));
    float as0 = asrc[sc0 * 4 + hdB], as1 = asrc[sc1 * 4 + hdB];
    const uint4 row0 = *(const uint4*)(hp16 + (size_t)sc0 * 128 + cb);
    const uint4 row1 = *(const uint4*)(hp16 + (size_t)sc1 * 128 + cb);
    float l0 = as0 + advB + ae0; l0 = fmaxf(l0, 0.2f * l0);
    float l1 = as1 + advB + ae1v; l1 = fmaxf(l1, 0.2f * l1);
    float w0 = (i0 < s1) ? __expf(l0) : 0.f;
    float w1 = (i1 < s1) ? __expf(l1) : 0.f;
    ssp += w0 + w1;
    sap += ((i0 < s1) ? ae0 : 0.f) + ((i1 < s1) ? ae1v : 0.f);
    acc[0] += w0 * blo(row0.x) + w1 * blo(row1.x);
    acc[1] += w0 * bhi(row0.x) + w1 * bhi(row1.x);
    acc[2] += w0 * blo(row0.y) + w1 * blo(row1.y);
    acc[3] += w0 * bhi(row0.y) + w1 * bhi(row1.y);
    acc[4] += w0 * blo(row0.z) + w1 * blo(row1.z);
    acc[5] += w0 * bhi(row0.z) + w1 * bhi(row1.z);
    acc[6] += w0 * blo(row0.w) + w1 * blo(row1.w);
    acc[7] += w0 * bhi(row0.w) + w1 * bhi(row1.w);
    ra0 = nra0; rb0 = nrb0; ra1 = nra1; rb1 = nrb1;
  }
  // reduce across the 4 edge-groups
#pragma unroll
  for (int i = 0; i < 8; ++i) {
    acc[i] += __shfl_xor(acc[i], 16);
    acc[i] += __shfl_xor(acc[i], 32);
  }
  ssp += __shfl_xor(ssp, 16); ssp += __shfl_xor(ssp, 32);
  sap += __shfl_xor(sap, 16); sap += __shfl_xor(sap, 32);
  // self-loop (fill_value='mean' fold) + normalization
  const float degf = (float)(dg > 0 ? dg : 1);
  float asnB = asrc[n * 4 + hdB];
  float la = asnB + advB + sap / degf;
  la = fmaxf(la, 0.2f * la);
  float wsf = __expf(la);
  float inv = 1.f / (ssp + wsf + 1e-16f);
  // epilogue
  const uint4 rs4 = *(const uint4*)(hp16 + (size_t)n * 128 + cb);
  const uint4 rr4 = *(const uint4*)(feat16 + (size_t)n * 128 + cb);
  const float4 gb0 = *(const float4*)(gbias + cb);
  const float4 gb1 = *(const float4*)(gbias + cb + 4);
  float v[8];
  v[0] = (acc[0] + wsf * blo(rs4.x)) * inv + gb0.x + blo(rr4.x);
  v[1] = (acc[1] + wsf * bhi(rs4.x)) * inv + gb0.y + bhi(rr4.x);
  v[2] = (acc[2] + wsf * blo(rs4.y)) * inv + gb0.z + blo(rr4.y);
  v[3] = (acc[3] + wsf * bhi(rs4.y)) * inv + gb0.w + bhi(rr4.y);
  v[4] = (acc[4] + wsf * blo(rs4.z)) * inv + gb1.x + blo(rr4.z);
  v[5] = (acc[5] + wsf * bhi(rs4.z)) * inv + gb1.y + bhi(rr4.z);
  v[6] = (acc[6] + wsf * blo(rs4.w)) * inv + gb1.z + blo(rr4.w);
  v[7] = (acc[7] + wsf * bhi(rs4.w)) * inv + gb1.w + bhi(rr4.w);
  float sum = 0.f, sq = 0.f;
#pragma unroll
  for (int i = 0; i < 8; ++i) {
    v[i] = fminf(fmaxf(v[i], -10.f), 10.f);
    sum += v[i]; sq += v[i] * v[i];
  }
#pragma unroll
  for (int o = 1; o < 16; o <<= 1) {
    sum += __shfl_xor(sum, o);
    sq += __shfl_xor(sq, o);
  }
  float mu = sum * (1.f / 128.f);
  float var = sq * (1.f / 128.f) - mu * mu;
  float rstd = rsqrtf(var + 1e-5f);
  const float4 lw0 = *(const float4*)(lnw + cb);
  const float4 lw1 = *(const float4*)(lnw + cb + 4);
  const float4 lb0 = *(const float4*)(lnb + cb);
  const float4 lb1 = *(const float4*)(lnb + cb + 4);
  float y[8];
  y[0] = (v[0] - mu) * rstd * lw0.x + lb0.x;
  y[1] = (v[1] - mu) * rstd * lw0.y + lb0.y;
  y[2] = (v[2] - mu) * rstd * lw0.z + lb0.z;
  y[3] = (v[3] - mu) * rstd * lw0.w + lb0.w;
  y[4] = (v[4] - mu) * rstd * lw1.x + lb1.x;
  y[5] = (v[5] - mu) * rstd * lw1.y + lb1.y;
  y[6] = (v[6] - mu) * rstd * lw1.z + lb1.z;
  y[7] = (v[7] - mu) * rstd * lw1.w + lb1.w;
#pragma unroll
  for (int i = 0; i < 8; ++i) y[i] = y[i] > 0.f ? y[i] : expm1f(y[i]);
  if (g == 0) {
    if (FINAL) {
      float4 o0 = {y[0], y[1], y[2], y[3]};
      float4 o1 = {y[4], y[5], y[6], y[7]};
      *(float4*)(out32 + (size_t)n * 128 + cb) = o0;
      *(float4*)(out32 + (size_t)n * 128 + cb + 4) = o1;
    } else {
      uint4 o;
      o.x = (unsigned)f2b(y[0]) | ((unsigned)f2b(y[1]) << 16);
      o.y = (unsigned)f2b(y[2]) | ((unsigned)f2b(y[3]) << 16);
      o.z = (unsigned)f2b(y[4]) | ((unsigned)f2b(y[5]) << 16);
      o.w = (unsigned)f2b(y[6]) | ((unsigned)f2b(y[7]) << 16);
      *(uint4*)(gout16 + (size_t)n * 128 + cb) = o;
    }
  }
}

// ---------- launch ----------
extern "C" void kernel_launch(void* const* d_in, const int* in_sizes, int n_in,
                              void* d_out, int out_size, void* d_ws, size_t ws_size,
                              hipStream_t stream) {
  const float* x      = (const float*)d_in[0];
  const float* etime  = (const float*)d_in[1];
  const float* ip_w1  = (const float*)d_in[2];
  const float* ip_b1  = (const float*)d_in[3];
  const float* ip_lnw = (const float*)d_in[4];
  const float* ip_lnb = (const float*)d_in[5];
  const float* ip_w2  = (const float*)d_in[6];
  const float* ip_b2  = (const float*)d_in[7];
  const float* pn_w   = (const float*)d_in[8];
  const float* pn_b   = (const float*)d_in[9];
  const float* ta_w1  = (const float*)d_in[10];
  const float* ta_b1  = (const float*)d_in[11];
  const float* ta_lnw = (const float*)d_in[12];
  const float* ta_lnb = (const float*)d_in[13];
  const float* ta_w2  = (const float*)d_in[14];
  const float* ta_b2  = (const float*)d_in[15];
  const float* g1_w   = (const float*)d_in[16];
  const float* g1_as  = (const float*)d_in[17];
  const float* g1_ad  = (const float*)d_in[18];
  const float* g1_ew  = (const float*)d_in[19];
  const float* g1_ae  = (const float*)d_in[20];
  const float* g1_b   = (const float*)d_in[21];
  const float* g2_w   = (const float*)d_in[22];
  const float* g2_as  = (const float*)d_in[23];
  const float* g2_ad  = (const float*)d_in[24];
  const float* g2_ew  = (const float*)d_in[25];
  const float* g2_ae  = (const float*)d_in[26];
  const float* g2_b   = (const float*)d_in[27];
  const float* n1_w   = (const float*)d_in[28];
  const float* n1_b   = (const float*)d_in[29];
  const float* n2_w   = (const float*)d_in[30];
  const float* n2_b   = (const float*)d_in[31];
  const int* eidx     = (const int*)d_in[32];
  const int* srcv = eidx;
  const int* dstv = eidx + NE;

  char* p = (char*)d_ws;
  auto carve = [&](size_t bytes) -> char* {
    char* r = p;
    p += (bytes + 255) & ~(size_t)255;
    return r;
  };
  u16*   h16    = (u16*)carve((size_t)NN * 128 * 2);
  u16*   g16    = (u16*)carve((size_t)NN * 128 * 2);
  u16*   hp16   = (u16*)carve((size_t)NN * 128 * 2);
  float* asrc   = (float*)carve((size_t)NN * 4 * 4);
  float* adst   = (float*)carve((size_t)NN * 4 * 4);
  u16*   recs   = (u16*)carve((size_t)NE * 32);
  int*   deg    = (int*)carve((size_t)NN * 4);
  int*   indptr = (int*)carve((size_t)(NN + 1) * 4);
  int*   cursor = (int*)carve((size_t)NN * 4);
  int*   blks   = (int*)carve(512 * 4);
  float* V      = (float*)carve(128 * 8 * 4);
  float* tbl    = (float*)carve((size_t)TBLN * 8 * 4);
  u16*   w1t    = (u16*)carve(128 * 256 * 2);
  u16*   w2t    = (u16*)carve(256 * 128 * 2);
  u16*   g1wt   = (u16*)carve(128 * 128 * 2);
  u16*   g2wt   = (u16*)carve(128 * 128 * 2);
  // x16 aliases g16: x16 written in prep_k, last read in fillip_k's GEMM1;
  // g16 first written by agg_k<0>, which launches after fillip. Stream-serialized.
  u16*   x16    = (u16*)g16;

  hipMemsetAsync(deg, 0, (size_t)NN * 4, stream);

  const int SCB = (NN + 511) / 512;  // 98

  prep_k<<<1 + 384 + FB + FB, 256, 0, stream>>>(g1_ew, g1_ae, g2_ew, g2_ae, V,
                                                ip_w1, ip_w2, g1_w, g2_w,
                                                w1t, w2t, g1wt, g2wt, dstv, deg,
                                                x, x16);
  build_table<<<TBLN, 128, 0, stream>>>(ta_w1, ta_b1, ta_lnw, ta_lnb, ta_w2, ta_b2, V, tbl);
  scan1<<<SCB, 512, 0, stream>>>(deg, indptr, blks);
  scan23<<<SCB, 512, 0, stream>>>(indptr, blks, deg, cursor, SCB);
  // fill + {ip GEMM1/2 + fused hp1 GEMM3} -> h16, hp16, asrc, adst, recs
  fillip_k<<<MB64 + FB, 256, 0, stream>>>(srcv, dstv, etime, tbl, cursor, recs,
                                          x16, w1t, ip_b1, ip_lnw, ip_lnb, w2t, ip_b2,
                                          pn_w, pn_b, h16,
                                          g1wt, g1_as, g1_ad, hp16, asrc, adst);
  // agg layer 1
  agg_k<0, 0><<<NN / 4, 256, 0, stream>>>(indptr, recs, asrc, adst, hp16, h16,
                                          g1_b, n1_w, n1_b, g16, nullptr);
  // layer-2 projection
  hp_mfma<<<MB64, 256, 0, stream>>>(g16, g2wt, g2_as, g2_ad, hp16, asrc, adst);
  // agg layer 2 (final)
  agg_k<1, 1><<<NN / 4, 256, 0, stream>>>(indptr, recs, asrc, adst, hp16, g16,
                                          g2_b, n2_w, n2_b, nullptr, (float*)d_out);
}